// Round 6
// baseline (56.740 us; speedup 1.0000x reference)
//
#include <hip/hip_runtime.h>

#define NUM_BINS 15
#define NUM_CLASSES 19
#define HW 262144          // 512*512
#define BATCH 8
#define BLOCK 256

typedef float f32x4 __attribute__((ext_vector_type(4)));

// 4 pixels/thread, float4 (16B/lane) loads+stores — isolates access width vs
// the R5 2-px version (55.7us, 4.2 TB/s). Binning uses the R5 fast path
// (1 true div per pixel + boundary guard) so VALU stays light; compiler is
// free to reload logits from L1/L2 (R5 lesson: reload schedule is ~free).
__global__ __launch_bounds__(BLOCK)
void Histogram_Binning_33818572488971_kernel(const float* __restrict__ logits,
                                             const float* __restrict__ val_freqs,
                                             float* __restrict__ out) {
    __shared__ float vf[NUM_CLASSES * NUM_BINS];
    for (int i = threadIdx.x; i < NUM_CLASSES * NUM_BINS; i += BLOCK)
        vf[i] = val_freqs[i];
    __syncthreads();

    const int t = blockIdx.x * BLOCK + threadIdx.x;     // quad index
    const int b  = t >> 16;                             // t / (HW/4), HW/4 = 65536
    const int s4 = (t & 65535) << 2;                    // starting pixel in image
    const size_t base = (size_t)b * NUM_CLASSES * HW + (size_t)s4;

    // ---- load 19 classes x 4 pixels ----
    float v[NUM_CLASSES][4];
#pragma unroll
    for (int c = 0; c < NUM_CLASSES; ++c) {
        const f32x4 q = *reinterpret_cast<const f32x4*>(logits + base + (size_t)c * HW);
        v[c][0] = q.x; v[c][1] = q.y; v[c][2] = q.z; v[c][3] = q.w;
    }

    // ---- softmax max + exp/sum (matches jax.nn.softmax numerics) ----
    float mx[4];
#pragma unroll
    for (int k = 0; k < 4; ++k) mx[k] = v[0][k];
#pragma unroll
    for (int c = 1; c < NUM_CLASSES; ++c)
#pragma unroll
        for (int k = 0; k < 4; ++k) mx[k] = fmaxf(mx[k], v[c][k]);

    float se[4] = {0.f, 0.f, 0.f, 0.f};
#pragma unroll
    for (int c = 0; c < NUM_CLASSES; ++c)
#pragma unroll
        for (int k = 0; k < 4; ++k) {
            const float e = expf(v[c][k] - mx[k]);
            v[c][k] = e;
            se[k] += e;
        }

    // ---- binning: fast path e*(15/se) with exactness guard ----
    // Ref is trunc(fl(fl(e/se)*15)). Fast path differs by <= ~4 ulp; only
    // when x is within 1e-4 of an integer boundary recompute exactly.
    float r[4];
#pragma unroll
    for (int k = 0; k < 4; ++k) r[k] = 15.0f / se[k];   // 1 true div per pixel

    float cs[4] = {0.f, 0.f, 0.f, 0.f};
#pragma unroll
    for (int c = 0; c < NUM_CLASSES; ++c)
#pragma unroll
        for (int k = 0; k < 4; ++k) {
            const float e = v[c][k];
            const float x = e * r[k];
            const float fl = floorf(x);
            int bin;
            if (__builtin_expect((x - fl < 1e-4f) | ((fl + 1.0f) - x < 1e-4f), 0)) {
                bin = (int)((e / se[k]) * 15.0f);        // exact ref rounding
            } else {
                bin = (int)fl;
            }
            bin = min(max(bin, 0), NUM_BINS - 1);
            const float cal = vf[c * NUM_BINS + bin];
            v[c][k] = cal;
            cs[k] += cal;
        }

    // ---- normalize over class dim (s==0 -> 1 guard, per reference) ----
    float inv[4];
#pragma unroll
    for (int k = 0; k < 4; ++k)
        inv[k] = 1.0f / ((cs[k] == 0.f) ? 1.f : cs[k]);

    // ---- 16B non-temporal stores ----
#pragma unroll
    for (int c = 0; c < NUM_CLASSES; ++c) {
        f32x4 q;
        q.x = v[c][0] * inv[0];
        q.y = v[c][1] * inv[1];
        q.z = v[c][2] * inv[2];
        q.w = v[c][3] * inv[3];
        __builtin_nontemporal_store(q, reinterpret_cast<f32x4*>(out + base + (size_t)c * HW));
    }
}

extern "C" void kernel_launch(void* const* d_in, const int* in_sizes, int n_in,
                              void* d_out, int out_size, void* d_ws, size_t ws_size,
                              hipStream_t stream) {
    const float* logits    = (const float*)d_in[0];   // [8,19,512,512] fp32
    const float* val_freqs = (const float*)d_in[1];   // [19,15] fp32
    float* out             = (float*)d_out;           // [8,19,512,512] fp32

    const int total_quads = BATCH * (HW / 4);           // 524,288 threads
    const int grid = total_quads / BLOCK;               // 2048 blocks (exact)

    Histogram_Binning_33818572488971_kernel<<<grid, BLOCK, 0, stream>>>(
        logits, val_freqs, out);
}